// Round 1
// baseline (59.864 us; speedup 1.0000x reference)
//
#include <hip/hip_runtime.h>

#define B_DIM 32
#define T_DIM 4096
#define D_DIM 512
#define E_DIM 512
#define EPS_K 1e-7f

// ---------------------------------------------------------------------------
// Kernel 1: yp[b,d] = sum_e y[b,e] * W[d,e]   (yp = y @ W^T)
// grid (B, D/64), 64 threads; y[b,:] staged in LDS (broadcast reads, free).
// ---------------------------------------------------------------------------
__global__ __launch_bounds__(64) void yp_kernel(const float* __restrict__ y,
                                                const float* __restrict__ W,
                                                float* __restrict__ yp) {
    const int b = blockIdx.x;
    const int d = blockIdx.y * 64 + threadIdx.x;
    __shared__ float ys[E_DIM];
    {
        const float4* src = (const float4*)(y + (size_t)b * E_DIM);
        float4* dst = (float4*)ys;
        dst[threadIdx.x]      = src[threadIdx.x];       // 64 * 16B
        dst[threadIdx.x + 64] = src[threadIdx.x + 64];  // covers 512 floats
    }
    __syncthreads();
    const float* Wr = W + (size_t)d * E_DIM;
    float acc = 0.f;
#pragma unroll 8
    for (int e = 0; e < E_DIM; e += 4) {
        float4 w4 = *(const float4*)(Wr + e);
        acc = fmaf(w4.x, ys[e],     acc);
        acc = fmaf(w4.y, ys[e + 1], acc);
        acc = fmaf(w4.z, ys[e + 2], acc);
        acc = fmaf(w4.w, ys[e + 3], acc);
    }
    yp[(size_t)b * D_DIM + d] = acc;
}

// ---------------------------------------------------------------------------
// Kernel 2: a_raw[b,t] = exp(tanh(dot(x[b,t,:], yp[b,:]) + bias)) * mask[b,t]
// grid (T/32, B), 256 threads = 4 waves; each wave handles 8 consecutive t.
// Lane l keeps yp[4l..4l+3] and yp[256+4l..] in registers (loaded once).
// x reads: 2 coalesced float4 loads per t per lane (1 KB per instruction).
// ---------------------------------------------------------------------------
__global__ __launch_bounds__(256) void score_kernel(const float* __restrict__ x,
                                                    const float* __restrict__ yp,
                                                    const float* __restrict__ bias,
                                                    const int* __restrict__ mask,
                                                    float* __restrict__ a_raw) {
    const int b    = blockIdx.y;
    const int wave = threadIdx.x >> 6;
    const int lane = threadIdx.x & 63;
    const int t0   = blockIdx.x * 32 + wave * 8;

    const float4* ypv = (const float4*)(yp + (size_t)b * D_DIM);
    const float4 w0 = ypv[lane];
    const float4 w1 = ypv[lane + 64];
    const float bv = bias[0];

    const size_t xbase = ((size_t)b * T_DIM + (size_t)t0) * D_DIM;
    const float4* xv = (const float4*)(x + xbase);

    for (int i = 0; i < 8; ++i) {
        const float4 x0 = xv[i * (D_DIM / 4) + lane];
        const float4 x1 = xv[i * (D_DIM / 4) + lane + 64];
        float p = x0.x * w0.x + x0.y * w0.y + x0.z * w0.z + x0.w * w0.w
                + x1.x * w1.x + x1.y * w1.y + x1.z * w1.z + x1.w * w1.w;
#pragma unroll
        for (int off = 32; off > 0; off >>= 1) p += __shfl_xor(p, off);
        if (lane == 0) {
            const int t = t0 + i;
            const float s = p + bv;
            const float e = expf(tanhf(s));
            const float a = mask[(size_t)b * T_DIM + t] ? e : 0.f;
            a_raw[(size_t)b * T_DIM + t] = a;
        }
    }
}

// ---------------------------------------------------------------------------
// Kernel 3: out[b,t] = a_raw[b,t] / (sum_t a_raw[b,:] + EPS)
// grid B, 1024 threads; deterministic fixed-tree reduction (no atomics).
// ---------------------------------------------------------------------------
__global__ __launch_bounds__(1024) void norm_kernel(const float* __restrict__ a_raw,
                                                    float* __restrict__ out) {
    const int b   = blockIdx.x;
    const int tid = threadIdx.x;
    const float4 v = ((const float4*)(a_raw + (size_t)b * T_DIM))[tid];
    float s = v.x + v.y + v.z + v.w;
#pragma unroll
    for (int off = 32; off > 0; off >>= 1) s += __shfl_xor(s, off);

    __shared__ float wsum[16];
    __shared__ float inv_s;
    const int wave = tid >> 6;
    const int lane = tid & 63;
    if (lane == 0) wsum[wave] = s;
    __syncthreads();
    if (tid == 0) {
        float tot = 0.f;
        for (int i = 0; i < 16; ++i) tot += wsum[i];  // fixed order: deterministic
        inv_s = 1.0f / (tot + EPS_K);
    }
    __syncthreads();
    const float inv = inv_s;
    const float4 o = make_float4(v.x * inv, v.y * inv, v.z * inv, v.w * inv);
    ((float4*)(out + (size_t)b * T_DIM))[tid] = o;
}

// ---------------------------------------------------------------------------
extern "C" void kernel_launch(void* const* d_in, const int* in_sizes, int n_in,
                              void* d_out, int out_size, void* d_ws, size_t ws_size,
                              hipStream_t stream) {
    const float* x    = (const float*)d_in[0];  // [B,T,D]
    const float* y    = (const float*)d_in[1];  // [B,E]
    const float* W    = (const float*)d_in[2];  // [D,E]
    const float* bias = (const float*)d_in[3];  // [1]
    const int*   mask = (const int*)d_in[4];    // [B,T] (bool -> int32 per harness)
    float* out = (float*)d_out;                 // [B,T]

    float* yp    = (float*)d_ws;                // B*D floats   = 64 KB
    float* a_raw = yp + B_DIM * D_DIM;          // B*T floats   = 512 KB

    yp_kernel<<<dim3(B_DIM, D_DIM / 64), 64, 0, stream>>>(y, W, yp);
    score_kernel<<<dim3(T_DIM / 32, B_DIM), 256, 0, stream>>>(x, yp, bias, mask, a_raw);
    norm_kernel<<<B_DIM, 1024, 0, stream>>>(a_raw, out);
}

// Round 2
// 50.806 us; speedup vs baseline: 1.1783x; 1.1783x over previous
//
#include <hip/hip_runtime.h>

#define B_DIM 32
#define T_DIM 4096
#define D_DIM 512
#define E_DIM 512
#define EPS_K 1e-7f

// ---------------------------------------------------------------------------
// Kernel 1: yp[b,d] = sum_e y[b,e] * W[d,e]   (yp = y @ W^T)
// One wave per (b,d): lanes across e, fully coalesced float4 loads of W row
// and y row, 6-step butterfly reduce. grid (D/4, B) x 256 thr = 16384 waves.
// W re-read per b is L2/L3-resident (1 MB).
// ---------------------------------------------------------------------------
__global__ __launch_bounds__(256) void yp_kernel(const float* __restrict__ y,
                                                 const float* __restrict__ W,
                                                 float* __restrict__ yp) {
    const int b    = blockIdx.y;
    const int wave = threadIdx.x >> 6;
    const int lane = threadIdx.x & 63;
    const int d    = blockIdx.x * 4 + wave;

    const float4* Wv = (const float4*)(W + (size_t)d * E_DIM);
    const float4* yv = (const float4*)(y + (size_t)b * E_DIM);
    const float4 w0 = Wv[lane];
    const float4 w1 = Wv[lane + 64];
    const float4 y0 = yv[lane];
    const float4 y1 = yv[lane + 64];

    float p = w0.x * y0.x + w0.y * y0.y + w0.z * y0.z + w0.w * y0.w
            + w1.x * y1.x + w1.y * y1.y + w1.z * y1.z + w1.w * y1.w;
#pragma unroll
    for (int off = 32; off > 0; off >>= 1) p += __shfl_xor(p, off);

    if (lane == 0) yp[(size_t)b * D_DIM + d] = p;
}

// ---------------------------------------------------------------------------
// Kernel 2: a_raw[b,t] = exp(tanh(dot(x[b,t,:], yp[b,:]) + bias)) * mask[b,t]
// grid (T/32, B), 256 threads = 4 waves; each wave handles 8 consecutive t.
// All 16 float4 x-loads issued up front; 8 independent butterfly reduces
// interleave for ILP; lanes 0..7 finish the 8 rows in parallel (coalesced).
// ---------------------------------------------------------------------------
__global__ __launch_bounds__(256) void score_kernel(const float* __restrict__ x,
                                                    const float* __restrict__ yp,
                                                    const float* __restrict__ bias,
                                                    const int* __restrict__ mask,
                                                    float* __restrict__ a_raw) {
    const int b    = blockIdx.y;
    const int wave = threadIdx.x >> 6;
    const int lane = threadIdx.x & 63;
    const int t0   = blockIdx.x * 32 + wave * 8;

    const float4* ypv = (const float4*)(yp + (size_t)b * D_DIM);
    const float4 w0 = ypv[lane];
    const float4 w1 = ypv[lane + 64];

    const float4* xv = (const float4*)(x + ((size_t)b * T_DIM + (size_t)t0) * D_DIM);

    // Issue all 16 streaming loads first (64 VGPRs of x in flight).
    float4 xa[8], xb[8];
#pragma unroll
    for (int i = 0; i < 8; ++i) {
        xa[i] = xv[i * (D_DIM / 4) + lane];
        xb[i] = xv[i * (D_DIM / 4) + lane + 64];
    }

    float p[8];
#pragma unroll
    for (int i = 0; i < 8; ++i) {
        p[i] = xa[i].x * w0.x + xa[i].y * w0.y + xa[i].z * w0.z + xa[i].w * w0.w
             + xb[i].x * w1.x + xb[i].y * w1.y + xb[i].z * w1.z + xb[i].w * w1.w;
    }

    // 8 independent butterfly reduces, interleaved per step for ILP.
#pragma unroll
    for (int off = 32; off > 0; off >>= 1) {
#pragma unroll
        for (int i = 0; i < 8; ++i) p[i] += __shfl_xor(p[i], off);
    }

    // Every lane now holds all 8 sums; lanes 0..7 finalize row t0+lane.
    if (lane < 8) {
        float s = (lane == 0) ? p[0] : (lane == 1) ? p[1] : (lane == 2) ? p[2]
                : (lane == 3) ? p[3] : (lane == 4) ? p[4] : (lane == 5) ? p[5]
                : (lane == 6) ? p[6] : p[7];
        const int t = t0 + lane;
        const float e = expf(tanhf(s + bias[0]));
        const float a = mask[(size_t)b * T_DIM + t] ? e : 0.f;
        a_raw[(size_t)b * T_DIM + t] = a;
    }
}

// ---------------------------------------------------------------------------
// Kernel 3: out[b,t] = a_raw[b,t] / (sum_t a_raw[b,:] + EPS)
// grid B, 1024 threads; deterministic fixed-tree reduction (no atomics).
// ---------------------------------------------------------------------------
__global__ __launch_bounds__(1024) void norm_kernel(const float* __restrict__ a_raw,
                                                    float* __restrict__ out) {
    const int b   = blockIdx.x;
    const int tid = threadIdx.x;
    const float4 v = ((const float4*)(a_raw + (size_t)b * T_DIM))[tid];
    float s = v.x + v.y + v.z + v.w;
#pragma unroll
    for (int off = 32; off > 0; off >>= 1) s += __shfl_xor(s, off);

    __shared__ float wsum[16];
    __shared__ float inv_s;
    const int wave = tid >> 6;
    const int lane = tid & 63;
    if (lane == 0) wsum[wave] = s;
    __syncthreads();
    if (tid == 0) {
        float tot = 0.f;
        for (int i = 0; i < 16; ++i) tot += wsum[i];  // fixed order: deterministic
        inv_s = 1.0f / (tot + EPS_K);
    }
    __syncthreads();
    const float inv = inv_s;
    const float4 o = make_float4(v.x * inv, v.y * inv, v.z * inv, v.w * inv);
    ((float4*)(out + (size_t)b * T_DIM))[tid] = o;
}

// ---------------------------------------------------------------------------
extern "C" void kernel_launch(void* const* d_in, const int* in_sizes, int n_in,
                              void* d_out, int out_size, void* d_ws, size_t ws_size,
                              hipStream_t stream) {
    const float* x    = (const float*)d_in[0];  // [B,T,D]
    const float* y    = (const float*)d_in[1];  // [B,E]
    const float* W    = (const float*)d_in[2];  // [D,E]
    const float* bias = (const float*)d_in[3];  // [1]
    const int*   mask = (const int*)d_in[4];    // [B,T] (bool -> int32 per harness)
    float* out = (float*)d_out;                 // [B,T]

    float* yp    = (float*)d_ws;                // B*D floats   = 64 KB
    float* a_raw = yp + B_DIM * D_DIM;          // B*T floats   = 512 KB

    yp_kernel<<<dim3(D_DIM / 4, B_DIM), 256, 0, stream>>>(y, W, yp);
    score_kernel<<<dim3(T_DIM / 32, B_DIM), 256, 0, stream>>>(x, yp, bias, mask, a_raw);
    norm_kernel<<<B_DIM, 1024, 0, stream>>>(a_raw, out);
}